// Round 20
// baseline (49.039 us; speedup 1.0000x reference)
//
// RoutingFreeGate — v20: v15 skeleton, BN 128->256 (wave tile 32x128).
// v15 gemm is LDS-read-instruction-bound (4096 b128/CU = 20.5us); BN=256
// gives 0.75 reads/MFMA -> 3072/CU ~= 15.4us. 512 blocks, active ~256 =
// 1/CU all-concurrent; vmcnt ledger 12/12/0 (12 issues/step). Loop, staging
// order, epilogue = v15 (proven). Score sums 2 partials.
#include <hip/hip_runtime.h>
#include <hip/hip_bf16.h>
#include <math.h>

#define H_DIM 2048
#define R_DIM 512
#define NTOK  16384
#define BM    64
#define BN    256
#define BK    64
#define KST   (H_DIM / BK)           // 32
#define NEG_BIG (-1.0e30f)           // finite in f32 AND after bf16 rounding

typedef __attribute__((ext_vector_type(8))) short bf16x8;
typedef __attribute__((ext_vector_type(4))) float f32x4;

static __device__ __forceinline__ unsigned short f2bf(float f) {
    __hip_bfloat16 h = __float2bfloat16(f);   // RNE
    return *reinterpret_cast<unsigned short*>(&h);
}

static __device__ __forceinline__ bf16x8 pack8(float4 lo, float4 hi) {
    union { bf16x8 v; unsigned short u[8]; } t;
    t.u[0] = f2bf(lo.x); t.u[1] = f2bf(lo.y); t.u[2] = f2bf(lo.z); t.u[3] = f2bf(lo.w);
    t.u[4] = f2bf(hi.x); t.u[5] = f2bf(hi.y); t.u[6] = f2bf(hi.z); t.u[7] = f2bf(hi.w);
    return t.v;
}

static __device__ __forceinline__ void gll16(const void* g, void* l) {
    __builtin_amdgcn_global_load_lds(
        (const __attribute__((address_space(1))) unsigned int*)g,
        (__attribute__((address_space(3))) unsigned int*)l,
        16, 0, 0);
}

// ---------------------------------------------------------------------------
// Aux: blocks 0-127 wcvt (W -> bf16 K-major Wb), block 128 scan (mask ->
// vidx/nv). (Unchanged from v15.)
// ---------------------------------------------------------------------------
__global__ __launch_bounds__(1024) void rfg20_aux(
    const float* __restrict__ W, unsigned short* __restrict__ Wb,
    const unsigned char* __restrict__ msk,
    int* __restrict__ vidx, int* __restrict__ nv_out)
{
    __shared__ int Wt[16];
    __shared__ int Wbase[16];
    const int b   = blockIdx.x;
    const int tid = threadIdx.x;

    if (b < 128) {
        const int i  = b * 1024 + tid;       // 0..131071
        const int r  = i >> 8;               // 0..511
        const int k8 = i & 255;              // 0..255
        const float* src = W + (size_t)r * H_DIM + k8 * 8;
        float4 a = *reinterpret_cast<const float4*>(src);
        float4 c = *reinterpret_cast<const float4*>(src + 4);
        *reinterpret_cast<bf16x8*>(Wb + ((size_t)k8 * R_DIM + r) * 8) = pack8(a, c);
    } else {
        const int lane = tid & 63;
        const int wv   = tid >> 6;
        union { uint4 v; unsigned char c[16]; } u;
        u.v = *reinterpret_cast<const uint4*>(msk + tid * 16);
        const unsigned int s4 = u.v.x + u.v.y + u.v.z + u.v.w;  // bytes<=4
        const int cnt = (s4 & 0xFF) + ((s4 >> 8) & 0xFF)
                      + ((s4 >> 16) & 0xFF) + (s4 >> 24);
        int pfx = cnt;
        #pragma unroll
        for (int off = 1; off < 64; off <<= 1) {
            const int t = __shfl_up(pfx, off, 64);
            if (lane >= off) pfx += t;
        }
        if (lane == 63) Wt[wv] = pfx;
        __syncthreads();
        if (tid == 0) {
            int run = 0;
            for (int i = 0; i < 16; ++i) { Wbase[i] = run; run += Wt[i]; }
        }
        __syncthreads();
        int p = Wbase[wv] + pfx - cnt;
        #pragma unroll
        for (int j = 0; j < 16; ++j)
            if (u.c[j]) vidx[p++] = tid * 16 + j;
        if (tid == 1023) {
            const int total = Wbase[15] + Wt[15];
            nv_out[0] = total;
            const int pe = (total + 63) & ~63;
            for (int i = total; i < pe; ++i) vidx[i] = 0;
        }
    }
}

// ---------------------------------------------------------------------------
// Compacted GEMM 64x256, BK=64, 256 thr / 4 waves (2x2 of 32x128), acc[2][8],
// counted-vmcnt 2-barrier loop, lookahead-2 (v15 skeleton). Inactive blocks
// (m0 >= nv) grid-stride-zero invalid hidden rows.
// ---------------------------------------------------------------------------
__global__ __launch_bounds__(256, 1) void rfg20_gemm(
    const float* __restrict__ x,
    const unsigned char* __restrict__ msk,
    const unsigned short* __restrict__ Wb,
    const int* __restrict__ vidx,
    const int* __restrict__ nvp,
    float* __restrict__ part,            // [2][NTOK] sumsq partials
    float* __restrict__ hid)
{
    __shared__ __align__(16) float4 As[2][1024];    // [buf][row*16+chunk] 32 KiB
    __shared__ __align__(16) short  Bs[2][2048][8]; // [buf][k8*256+col]   64 KiB
    __shared__ float Ps[2][BM];
    __shared__ int   Vr[BM];
    __shared__ int   Vv[BM];

    const int nv  = nvp[0];
    const int tid = threadIdx.x;
    // XCD swizzle: 2 n-tiles of an m-panel -> same XCD.
    const int bid   = blockIdx.x;            // 512 blocks
    const int xcd   = bid & 7;
    const int local = bid >> 3;              // 0..63
    const int nt    = local & 1;
    const int mt    = (local >> 1) * 8 + xcd;  // bijective 0..255
    const int m0    = mt * BM;

    if (m0 >= nv) {
        // ---- inactive block: zero invalid hidden rows (grid-stride) ----
        const int mt_min = (nv + 63) >> 6;
        const int Z = (256 - mt_min) * 2;            // # inactive blocks
        const int z = (mt - mt_min) * 2 + nt;        // ordinal in [0, Z)
        const float2 z2 = make_float2(0.f, 0.f);
        for (int t = z; t < NTOK; t += Z)
            if (!msk[t])
                *reinterpret_cast<float2*>(&hid[(size_t)t * R_DIM + tid * 2]) = z2;
        return;
    }
    const int n0 = nt * BN;

    const int w  = tid >> 6;
    const int l  = tid & 63;
    const int wr = w >> 1;               // 0..1: 32-row group
    const int wc = w & 1;                // 0..1: 128-col group
    const int fr = l & 15;
    const int fg = l >> 4;               // k-subgroup 0..3

    // vidx gathers issued BEFORE the stages (oldest in VMEM queue) so the
    // invariant "newest 12 ops == stage(ks+1)" holds at every vmcnt(12).
    int vrj[4];
    #pragma unroll
    for (int j = 0; j < 4; ++j)
        vrj[j] = vidx[m0 + (tid >> 4) + 16 * j];
    if (tid < BM) {
        Vr[tid] = vidx[m0 + tid];
        Vv[tid] = (m0 + tid) < nv;
    }

    f32x4 acc[2][8] = {};

#define RFG20_STAGE(ks_, buf_) do {                                      \
        const int _kA = (ks_) * BK;                                      \
        _Pragma("unroll")                                                \
        for (int j = 0; j < 4; ++j) {                                    \
            const int idx = j * 256 + tid;                               \
            const int row = idx >> 4, cL = idx & 15;                     \
            const int cG  = cL ^ (row & 7);                              \
            gll16(x + (size_t)vrj[j] * H_DIM + _kA + cG * 4,             \
                  (char*)&As[buf_][0] + idx * 16);                       \
        }                                                                \
        _Pragma("unroll")                                                \
        for (int j = 0; j < 8; ++j)                                      \
            gll16(Wb + ((size_t)((ks_) * 8 + j) * R_DIM + n0 + tid) * 8, \
                  (char*)&Bs[buf_][0][0] + j * 4096 + tid * 16);         \
    } while (0)

    // Phase body: READS(buf) -> lgkm0 -> barrier -> STAGE(ks+2 -> buf) -> MFMA
#define RFG20_BODY(ks_, buf_, stage_)  do {                              \
        bf16x8 bfr[2][8];                                                \
        _Pragma("unroll")                                                \
        for (int kk = 0; kk < 2; ++kk)                                   \
            _Pragma("unroll")                                            \
            for (int ni = 0; ni < 8; ++ni)                               \
                bfr[kk][ni] = *reinterpret_cast<const bf16x8*>(          \
                    &Bs[buf_][(kk * 4 + fg) * 256 + wc * 128 + ni * 16 + fr][0]); \
        bf16x8 afr[2][2];                                                \
        _Pragma("unroll")                                                \
        for (int mi = 0; mi < 2; ++mi) {                                 \
            const int row = wr * 32 + mi * 16 + fr;                      \
            const int s   = row & 7;                                     \
            _Pragma("unroll")                                            \
            for (int kk = 0; kk < 2; ++kk) {                             \
                const int g0 = kk * 8 + 2 * fg;                          \
                float4 lo = As[buf_][row * 16 + (g0 ^ s)];               \
                float4 hi = As[buf_][row * 16 + ((g0 + 1) ^ s)];         \
                afr[mi][kk] = pack8(lo, hi);                             \
            }                                                            \
        }                                                                \
        asm volatile("s_waitcnt lgkmcnt(0)" ::: "memory");               \
        __builtin_amdgcn_s_barrier();      /* all waves done reading buf */ \
        if (stage_) RFG20_STAGE((ks_) + 2, buf_);                        \
        __builtin_amdgcn_s_setprio(1);                                   \
        _Pragma("unroll")                                                \
        for (int kk = 0; kk < 2; ++kk)                                   \
            _Pragma("unroll")                                            \
            for (int mi = 0; mi < 2; ++mi)                               \
                _Pragma("unroll")                                        \
                for (int ni = 0; ni < 8; ++ni)                           \
                    acc[mi][ni] = __builtin_amdgcn_mfma_f32_16x16x32_bf16(\
                        afr[mi][kk], bfr[kk][ni], acc[mi][ni], 0, 0, 0); \
        __builtin_amdgcn_s_setprio(0);                                   \
    } while (0)

    RFG20_STAGE(0, 0);
    RFG20_STAGE(1, 1);

    for (int ks = 0; ks < KST - 2; ++ks) {       // 0..29: stage ks+2
        asm volatile("s_waitcnt vmcnt(12)" ::: "memory");  // stage(ks) done
        __builtin_amdgcn_s_barrier();
        RFG20_BODY(ks, (ks & 1), true);
    }
    {   // ks = KST-2: no stage; outstanding = stage(30)+stage(31) -> wait 12
        asm volatile("s_waitcnt vmcnt(12)" ::: "memory");
        __builtin_amdgcn_s_barrier();
        RFG20_BODY(KST - 2, ((KST - 2) & 1), false);
    }
    {   // ks = KST-1: drain
        asm volatile("s_waitcnt vmcnt(0)" ::: "memory");
        __builtin_amdgcn_s_barrier();
        RFG20_BODY(KST - 1, ((KST - 1) & 1), false);
    }
#undef RFG20_BODY
#undef RFG20_STAGE

    // ---- epilogue: norm partials, scattered C write ----
    #pragma unroll
    for (int mi = 0; mi < 2; ++mi) {
        #pragma unroll
        for (int r = 0; r < 4; ++r) {
            const int rowl = wr * 32 + mi * 16 + fg * 4 + r;
            float s = 0.0f;
            #pragma unroll
            for (int ni = 0; ni < 8; ++ni) {
                const float v = acc[mi][ni][r];
                s = fmaf(v, v, s);
            }
            #pragma unroll
            for (int off = 1; off < 16; off <<= 1)
                s += __shfl_xor(s, off, 64);
            if (fr == 0) Ps[wc][rowl] = s;
        }
    }

    #pragma unroll
    for (int mi = 0; mi < 2; ++mi)
        #pragma unroll
        for (int ni = 0; ni < 8; ++ni)
            #pragma unroll
            for (int r = 0; r < 4; ++r) {
                const int rowl = wr * 32 + mi * 16 + fg * 4 + r;
                if (Vv[rowl])
                    hid[(size_t)Vr[rowl] * R_DIM + n0 + wc * 128 + ni * 16 + fr] =
                        acc[mi][ni][r];
            }

    __syncthreads();
    if (tid < BM && Vv[tid])
        part[(size_t)nt * NTOK + Vr[tid]] = Ps[0][tid] + Ps[1][tid];
}

// ---------------------------------------------------------------------------
// Finish: sum the 2 n-tile partials, sqrt/scale/bias, gate. Unwritten part
// slots (invalid tokens) may hold garbage: nan-clamp + msk gate handle it.
// ---------------------------------------------------------------------------
__global__ __launch_bounds__(256) void rfg20_score(
    const unsigned char* __restrict__ msk,
    const float* __restrict__ gsc,
    const float* __restrict__ gbi,
    const float* __restrict__ part,
    float* __restrict__ om,
    float* __restrict__ os)
{
    const int t = blockIdx.x * 256 + threadIdx.x;
    const float s = part[t] + part[NTOK + t];
    float sc = sqrtf(s) * gsc[0] - gbi[0];
    if (!(sc > -1.0e30f && sc < 1.0e30f)) sc = 0.0f;  // never emit inf/nan
    const bool keep = (msk[t] != 0) && (sc >= 0.5f);
    om[t] = keep ? 1.0f : 0.0f;
    os[t] = keep ? sc : NEG_BIG;
}

extern "C" void kernel_launch(void* const* d_in, const int* in_sizes, int n_in,
                              void* d_out, int out_size, void* d_ws, size_t ws_size,
                              hipStream_t stream)
{
    const float*         x     = (const float*)d_in[0];
    const unsigned char* msk   = (const unsigned char*)d_in[1];  // jax bool = 1B
    const float*         W     = (const float*)d_in[2];
    const float*         scale = (const float*)d_in[3];
    const float*         bias  = (const float*)d_in[4];

    float* out = (float*)d_out;
    float* om  = out;               // [NTOK]
    float* os  = out + NTOK;        // [NTOK]
    float* hid = out + 2 * NTOK;    // [NTOK][R_DIM]

    char* ws = (char*)d_ws;
    unsigned short* Wb   = (unsigned short*)ws;                       // 2 MiB
    float*          part = (float*)(ws + 2 * 1024 * 1024);            // 128 KiB
    int*            vidx = (int*)(ws + 2 * 1024 * 1024 + 256 * 1024); // 64 KiB
    int*            nvp  = (int*)(ws + 2 * 1024 * 1024 + 320 * 1024); // 4 B

    rfg20_aux<<<129, 1024, 0, stream>>>(W, Wb, msk, vidx, nvp);
    rfg20_gemm<<<(NTOK / BM) * (R_DIM / BN), 256, 0, stream>>>(
        x, msk, Wb, vidx, nvp, part, hid);
    rfg20_score<<<NTOK / 256, 256, 0, stream>>>(msk, scale, bias, part, om, os);
}

// Round 21
// 40.409 us; speedup vs baseline: 1.2136x; 1.2136x over previous
//
// RoutingFreeGate — v21: restore v15 verbatim (best: 40.3 us). Sweep of all
// structural neighbors (v16-v20: reg-A, bf16-A-LDS, fences, BN=256) each
// regressed; v15 is the structural optimum of the 2-barrier counted-vmcnt
// class at this problem's parallelism budget. Symbols renamed only.
#include <hip/hip_runtime.h>
#include <hip/hip_bf16.h>
#include <math.h>

#define H_DIM 2048
#define R_DIM 512
#define NTOK  16384
#define BM    64
#define BN    128
#define BK    64
#define KST   (H_DIM / BK)           // 32
#define NEG_BIG (-1.0e30f)           // finite in f32 AND after bf16 rounding

typedef __attribute__((ext_vector_type(8))) short bf16x8;
typedef __attribute__((ext_vector_type(4))) float f32x4;

static __device__ __forceinline__ unsigned short f2bf(float f) {
    __hip_bfloat16 h = __float2bfloat16(f);   // RNE
    return *reinterpret_cast<unsigned short*>(&h);
}

static __device__ __forceinline__ bf16x8 pack8(float4 lo, float4 hi) {
    union { bf16x8 v; unsigned short u[8]; } t;
    t.u[0] = f2bf(lo.x); t.u[1] = f2bf(lo.y); t.u[2] = f2bf(lo.z); t.u[3] = f2bf(lo.w);
    t.u[4] = f2bf(hi.x); t.u[5] = f2bf(hi.y); t.u[6] = f2bf(hi.z); t.u[7] = f2bf(hi.w);
    return t.v;
}

static __device__ __forceinline__ void gll16(const void* g, void* l) {
    __builtin_amdgcn_global_load_lds(
        (const __attribute__((address_space(1))) unsigned int*)g,
        (__attribute__((address_space(3))) unsigned int*)l,
        16, 0, 0);
}

// ---------------------------------------------------------------------------
// Aux: blocks 0-127 wcvt (W -> bf16 K-major Wb), block 128 scan (mask ->
// vidx/nv). Invalid-row zeroing lives in the gemm's inactive blocks.
// ---------------------------------------------------------------------------
__global__ __launch_bounds__(1024) void rfg21_aux(
    const float* __restrict__ W, unsigned short* __restrict__ Wb,
    const unsigned char* __restrict__ msk,
    int* __restrict__ vidx, int* __restrict__ nv_out)
{
    __shared__ int Wt[16];
    __shared__ int Wbase[16];
    const int b   = blockIdx.x;
    const int tid = threadIdx.x;

    if (b < 128) {
        const int i  = b * 1024 + tid;       // 0..131071
        const int r  = i >> 8;               // 0..511
        const int k8 = i & 255;              // 0..255
        const float* src = W + (size_t)r * H_DIM + k8 * 8;
        float4 a = *reinterpret_cast<const float4*>(src);
        float4 c = *reinterpret_cast<const float4*>(src + 4);
        *reinterpret_cast<bf16x8*>(Wb + ((size_t)k8 * R_DIM + r) * 8) = pack8(a, c);
    } else {
        const int lane = tid & 63;
        const int wv   = tid >> 6;
        union { uint4 v; unsigned char c[16]; } u;
        u.v = *reinterpret_cast<const uint4*>(msk + tid * 16);
        const unsigned int s4 = u.v.x + u.v.y + u.v.z + u.v.w;  // bytes<=4
        const int cnt = (s4 & 0xFF) + ((s4 >> 8) & 0xFF)
                      + ((s4 >> 16) & 0xFF) + (s4 >> 24);
        int pfx = cnt;
        #pragma unroll
        for (int off = 1; off < 64; off <<= 1) {
            const int t = __shfl_up(pfx, off, 64);
            if (lane >= off) pfx += t;
        }
        if (lane == 63) Wt[wv] = pfx;
        __syncthreads();
        if (tid == 0) {
            int run = 0;
            for (int i = 0; i < 16; ++i) { Wbase[i] = run; run += Wt[i]; }
        }
        __syncthreads();
        int p = Wbase[wv] + pfx - cnt;
        #pragma unroll
        for (int j = 0; j < 16; ++j)
            if (u.c[j]) vidx[p++] = tid * 16 + j;
        if (tid == 1023) {
            const int total = Wbase[15] + Wt[15];
            nv_out[0] = total;
            const int pe = (total + 63) & ~63;
            for (int i = total; i < pe; ++i) vidx[i] = 0;
        }
    }
}

// ---------------------------------------------------------------------------
// Compacted GEMM 64x128, BK=64, 256 thr / 4 waves (2x2 of 32x64), acc[2][4],
// counted-vmcnt 2-barrier loop, lookahead-2 on a double buffer. Inactive
// blocks (m0 >= nv) grid-stride-zero invalid hidden rows.
// ---------------------------------------------------------------------------
__global__ __launch_bounds__(256, 2) void rfg21_gemm(
    const float* __restrict__ x,
    const unsigned char* __restrict__ msk,
    const unsigned short* __restrict__ Wb,
    const int* __restrict__ vidx,
    const int* __restrict__ nvp,
    float* __restrict__ part,            // [4][NTOK] sumsq partials
    float* __restrict__ hid)
{
    __shared__ __align__(16) float4 As[2][1024];    // [buf][row*16+chunk] 32 KiB
    __shared__ __align__(16) short  Bs[2][1024][8]; // [buf][k8*128+col]   32 KiB
    __shared__ float Ps[2][BM];
    __shared__ int   Vr[BM];
    __shared__ int   Vv[BM];

    const int nv  = nvp[0];
    const int tid = threadIdx.x;
    // XCD swizzle: 4 n-tiles of an m-panel -> same XCD.
    const int bid   = blockIdx.x;            // 1024 blocks
    const int xcd   = bid & 7;
    const int local = bid >> 3;              // 0..127
    const int nt    = local & 3;
    const int mt    = (local >> 2) * 8 + xcd;  // bijective 0..255
    const int m0    = mt * BM;

    if (m0 >= nv) {
        // ---- inactive block: zero invalid hidden rows (grid-stride) ----
        const int mt_min = (nv + 63) >> 6;
        const int Z = (256 - mt_min) * 4;            // # inactive blocks
        const int z = (mt - mt_min) * 4 + nt;        // ordinal in [0, Z)
        const float2 z2 = make_float2(0.f, 0.f);
        for (int t = z; t < NTOK; t += Z)
            if (!msk[t])
                *reinterpret_cast<float2*>(&hid[(size_t)t * R_DIM + tid * 2]) = z2;
        return;
    }
    const int n0 = nt * BN;

    const int w  = tid >> 6;
    const int l  = tid & 63;
    const int wr = w >> 1;               // 0..1: 32-row group
    const int wc = w & 1;                // 0..1: 64-col group
    const int fr = l & 15;
    const int fg = l >> 4;               // k-subgroup 0..3

    // vidx gathers issued BEFORE the stages (oldest in VMEM queue) so the
    // invariant "newest 8 ops == stage(ks+1)" holds at every vmcnt(8).
    int vrj[4];
    #pragma unroll
    for (int j = 0; j < 4; ++j)
        vrj[j] = vidx[m0 + (tid >> 4) + 16 * j];
    if (tid < BM) {
        Vr[tid] = vidx[m0 + tid];
        Vv[tid] = (m0 + tid) < nv;
    }

    f32x4 acc[2][4] = {};

#define RFG21_STAGE(ks_, buf_) do {                                      \
        const int _kA = (ks_) * BK;                                      \
        _Pragma("unroll")                                                \
        for (int j = 0; j < 4; ++j) {                                    \
            const int idx = j * 256 + tid;                               \
            const int row = idx >> 4, cL = idx & 15;                     \
            const int cG  = cL ^ (row & 7);                              \
            gll16(x + (size_t)vrj[j] * H_DIM + _kA + cG * 4,             \
                  (char*)&As[buf_][0] + idx * 16);                       \
        }                                                                \
        _Pragma("unroll")                                                \
        for (int j = 0; j < 4; ++j) {                                    \
            const int idx = j * 256 + tid;                               \
            const int k8 = idx >> 7, col = idx & 127;                    \
            gll16(Wb + ((size_t)((ks_) * 8 + k8) * R_DIM + n0 + col) * 8,\
                  (char*)&Bs[buf_][0][0] + idx * 16);                    \
        }                                                                \
    } while (0)

    // Phase body: READS(buf) -> lgkm0 -> barrier -> STAGE(ks+2 -> buf) -> MFMA
#define RFG21_BODY(ks_, buf_, stage_)  do {                              \
        bf16x8 bfr[2][4];                                                \
        _Pragma("unroll")                                                \
        for (int kk = 0; kk < 2; ++kk)                                   \
            _Pragma("unroll")                                            \
            for (int ni = 0; ni < 4; ++ni)                               \
                bfr[kk][ni] = *reinterpret_cast<const bf16x8*>(          \
                    &Bs[buf_][(kk * 4 + fg) * 128 + wc * 64 + ni * 16 + fr][0]); \
        bf16x8 afr[2][2];                                                \
        _Pragma("unroll")                                                \
        for (int mi = 0; mi < 2; ++mi) {                                 \
            const int row = wr * 32 + mi * 16 + fr;                      \
            const int s   = row & 7;                                     \
            _Pragma("unroll")                                            \
            for (int kk = 0; kk < 2; ++kk) {                             \
                const int g0 = kk * 8 + 2 * fg;                          \
                float4 lo = As[buf_][row * 16 + (g0 ^ s)];               \
                float4 hi = As[buf_][row * 16 + ((g0 + 1) ^ s)];         \
                afr[mi][kk] = pack8(lo, hi);                             \
            }                                                            \
        }                                                                \
        asm volatile("s_waitcnt lgkmcnt(0)" ::: "memory");               \
        __builtin_amdgcn_s_barrier();      /* all waves done reading buf */ \
        if (stage_) RFG21_STAGE((ks_) + 2, buf_);                        \
        __builtin_amdgcn_s_setprio(1);                                   \
        _Pragma("unroll")                                                \
        for (int kk = 0; kk < 2; ++kk)                                   \
            _Pragma("unroll")                                            \
            for (int mi = 0; mi < 2; ++mi)                               \
                _Pragma("unroll")                                        \
                for (int ni = 0; ni < 4; ++ni)                           \
                    acc[mi][ni] = __builtin_amdgcn_mfma_f32_16x16x32_bf16(\
                        afr[mi][kk], bfr[kk][ni], acc[mi][ni], 0, 0, 0); \
        __builtin_amdgcn_s_setprio(0);                                   \
    } while (0)

    RFG21_STAGE(0, 0);
    RFG21_STAGE(1, 1);

    for (int ks = 0; ks < KST - 2; ++ks) {       // 0..29: stage ks+2
        asm volatile("s_waitcnt vmcnt(8)" ::: "memory");  // stage(ks) done
        __builtin_amdgcn_s_barrier();
        RFG21_BODY(ks, (ks & 1), true);
    }
    {   // ks = KST-2: no stage
        asm volatile("s_waitcnt vmcnt(8)" ::: "memory");
        __builtin_amdgcn_s_barrier();
        RFG21_BODY(KST - 2, ((KST - 2) & 1), false);
    }
    {   // ks = KST-1: drain
        asm volatile("s_waitcnt vmcnt(0)" ::: "memory");
        __builtin_amdgcn_s_barrier();
        RFG21_BODY(KST - 1, ((KST - 1) & 1), false);
    }
#undef RFG21_BODY
#undef RFG21_STAGE

    // ---- epilogue: norm partials, scattered C write ----
    #pragma unroll
    for (int mi = 0; mi < 2; ++mi) {
        #pragma unroll
        for (int r = 0; r < 4; ++r) {
            const int rowl = wr * 32 + mi * 16 + fg * 4 + r;
            float s = 0.0f;
            #pragma unroll
            for (int ni = 0; ni < 4; ++ni) {
                const float v = acc[mi][ni][r];
                s = fmaf(v, v, s);
            }
            #pragma unroll
            for (int off = 1; off < 16; off <<= 1)
                s += __shfl_xor(s, off, 64);
            if (fr == 0) Ps[wc][rowl] = s;
        }
    }

    #pragma unroll
    for (int mi = 0; mi < 2; ++mi)
        #pragma unroll
        for (int ni = 0; ni < 4; ++ni)
            #pragma unroll
            for (int r = 0; r < 4; ++r) {
                const int rowl = wr * 32 + mi * 16 + fg * 4 + r;
                if (Vv[rowl])
                    hid[(size_t)Vr[rowl] * R_DIM + n0 + wc * 64 + ni * 16 + fr] =
                        acc[mi][ni][r];
            }

    __syncthreads();
    if (tid < BM && Vv[tid])
        part[(size_t)nt * NTOK + Vr[tid]] = Ps[0][tid] + Ps[1][tid];
}

// ---------------------------------------------------------------------------
// Finish: sum the 4 n-tile partials, sqrt/scale/bias, gate. Unwritten part
// slots (invalid tokens) may hold garbage: nan-clamp + msk gate handle it.
// ---------------------------------------------------------------------------
__global__ __launch_bounds__(256) void rfg21_score(
    const unsigned char* __restrict__ msk,
    const float* __restrict__ gsc,
    const float* __restrict__ gbi,
    const float* __restrict__ part,
    float* __restrict__ om,
    float* __restrict__ os)
{
    const int t = blockIdx.x * 256 + threadIdx.x;
    const float s = part[t] + part[NTOK + t] + part[2 * NTOK + t] + part[3 * NTOK + t];
    float sc = sqrtf(s) * gsc[0] - gbi[0];
    if (!(sc > -1.0e30f && sc < 1.0e30f)) sc = 0.0f;  // never emit inf/nan
    const bool keep = (msk[t] != 0) && (sc >= 0.5f);
    om[t] = keep ? 1.0f : 0.0f;
    os[t] = keep ? sc : NEG_BIG;
}

extern "C" void kernel_launch(void* const* d_in, const int* in_sizes, int n_in,
                              void* d_out, int out_size, void* d_ws, size_t ws_size,
                              hipStream_t stream)
{
    const float*         x     = (const float*)d_in[0];
    const unsigned char* msk   = (const unsigned char*)d_in[1];  // jax bool = 1B
    const float*         W     = (const float*)d_in[2];
    const float*         scale = (const float*)d_in[3];
    const float*         bias  = (const float*)d_in[4];

    float* out = (float*)d_out;
    float* om  = out;               // [NTOK]
    float* os  = out + NTOK;        // [NTOK]
    float* hid = out + 2 * NTOK;    // [NTOK][R_DIM]

    char* ws = (char*)d_ws;
    unsigned short* Wb   = (unsigned short*)ws;                       // 2 MiB
    float*          part = (float*)(ws + 2 * 1024 * 1024);            // 256 KiB
    int*            vidx = (int*)(ws + 2 * 1024 * 1024 + 256 * 1024); // 64 KiB
    int*            nvp  = (int*)(ws + 2 * 1024 * 1024 + 320 * 1024); // 4 B

    rfg21_aux<<<129, 1024, 0, stream>>>(W, Wb, msk, vidx, nvp);
    rfg21_gemm<<<(NTOK / BM) * (R_DIM / BN), 256, 0, stream>>>(
        x, msk, Wb, vidx, nvp, part, hid);
    rfg21_score<<<NTOK / 256, 256, 0, stream>>>(msk, scale, bias, part, om, os);
}